// Round 15
// baseline (99.312 us; speedup 1.0000x reference)
//
#include <hip/hip_runtime.h>
#include <cstdint>
#include <cmath>

#define DENSITY   0.05f
#define TOP_IG    7
#define NT        256
#define NT1       64
#define FEAT      4096
#define FEAT4     1024
#define NBINS     1024     // 10-bit pass-1 digit: key>>22 (sign+exp+1 mantissa bit)
#define CAPF      32       // finalist cap (typ 1-3)

typedef float vfloat4 __attribute__((ext_vector_type(4)));

// monotonic float -> uint order key (ascending float == ascending key)
__device__ __forceinline__ unsigned fkey(float f) {
    unsigned u = __float_as_uint(f);
    return (u & 0x80000000u) ? ~u : (u | 0x80000000u);
}
__device__ __forceinline__ float fkey_inv(unsigned k) {
    unsigned u = (k & 0x80000000u) ? (k & 0x7fffffffu) : ~k;
    return __uint_as_float(u);
}

// ---------------- kernel 1: chunked column partial sums (R12 geometry, frozen) ----------------
__global__ __launch_bounds__(NT1)
void k_colsum_partial(const float4* __restrict__ x4, float4* __restrict__ part4,
                      int B, int F4v, int rowsPerChunk) {
    int cg = blockIdx.x * NT1 + threadIdx.x;
    if (cg >= F4v) return;
    int r0 = blockIdx.y * rowsPerChunk;
    int r1 = r0 + rowsPerChunk; if (r1 > B) r1 = B;
    float4 s0 = make_float4(0.f,0.f,0.f,0.f), s1 = s0, s2 = s0, s3 = s0;
    int r = r0;
    for (; r + 4 <= r1; r += 4) {
        float4 a = x4[(size_t)(r+0) * F4v + cg];
        float4 b = x4[(size_t)(r+1) * F4v + cg];
        float4 c = x4[(size_t)(r+2) * F4v + cg];
        float4 d = x4[(size_t)(r+3) * F4v + cg];
        s0.x += a.x; s0.y += a.y; s0.z += a.z; s0.w += a.w;
        s1.x += b.x; s1.y += b.y; s1.z += b.z; s1.w += b.w;
        s2.x += c.x; s2.y += c.y; s2.z += c.z; s2.w += c.w;
        s3.x += d.x; s3.y += d.y; s3.z += d.z; s3.w += d.w;
    }
    for (; r < r1; ++r) {
        float4 a = x4[(size_t)r * F4v + cg];
        s0.x += a.x; s0.y += a.y; s0.z += a.z; s0.w += a.w;
    }
    float4 s = make_float4(s0.x+s1.x+s2.x+s3.x, s0.y+s1.y+s2.y+s3.y,
                           s0.z+s1.z+s2.z+s3.z, s0.w+s1.w+s2.w+s3.w);
    part4[(size_t)blockIdx.y * F4v + cg] = s;
}

// ------- kernel 2: reduce partials -> mean; factor + invFactor (frozen from R12) -------
__global__ __launch_bounds__(NT)
void k_finalize_stats(const float4* __restrict__ part4, const float4* __restrict__ aa4,
                      float4* __restrict__ mean4, float4* __restrict__ factor4,
                      float4* __restrict__ invf4, int B, int F4v, int nChunks) {
    __shared__ float4 red[16][17];
    const int c  = threadIdx.x >> 4;
    const int s  = threadIdx.x & 15;
    const int cg = blockIdx.x * 16 + c;
    float4 acc = make_float4(0.f, 0.f, 0.f, 0.f);
    if (cg < F4v) {
        for (int ch = s; ch < nChunks; ch += 16) {
            float4 v = part4[(size_t)ch * F4v + cg];
            acc.x += v.x; acc.y += v.y; acc.z += v.z; acc.w += v.w;
        }
    }
    red[c][s] = acc;
    __syncthreads();
    if (s == 0 && cg < F4v) {
        float4 t = red[c][0];
        #pragma unroll
        for (int i = 1; i < 16; ++i) {
            float4 v = red[c][i];
            t.x += v.x; t.y += v.y; t.z += v.z; t.w += v.w;
        }
        float invB = 1.0f / (float)B;
        mean4[cg] = make_float4(t.x * invB, t.y * invB, t.z * invB, t.w * invB);
        float4 a = aa4[cg];
        float fx = (float)exp((double)(DENSITY - a.x));
        float fy = (float)exp((double)(DENSITY - a.y));
        float fz = (float)exp((double)(DENSITY - a.z));
        float fw = (float)exp((double)(DENSITY - a.w));
        factor4[cg] = make_float4(fx, fy, fz, fw);
        invf4[cg]   = make_float4(1.0f / fx, 1.0f / fy, 1.0f / fz, 1.0f / fw);
    }
}

// wave inclusive scan + total of per-lane value
__device__ __forceinline__ void wscan(unsigned T, int lane, unsigned& incl, unsigned& tot) {
    unsigned P = T;
    #pragma unroll
    for (int off = 1; off < 64; off <<= 1) {
        unsigned n = __shfl_up(P, off, 64);
        if (lane >= off) P += n;
    }
    incl = P;
    tot = __shfl(P, 63, 64);
}

// find rank rr_in in a 256-bin histogram (lane owns 4 bins via uint4) — wave-level
__device__ __forceinline__ void select256(const unsigned* h, int lane,
                                          unsigned rr_in, unsigned& sub, unsigned& rr) {
    uint4 c = *reinterpret_cast<const uint4*>(&h[lane << 2]);
    unsigned T = c.x + c.y + c.z + c.w;
    unsigned incl, tot; wscan(T, lane, incl, tot);
    unsigned above = tot - incl;
    bool hit = (above < rr_in) && (rr_in <= above + T);
    unsigned long long mk = __ballot(hit);
    int src = __ffsll(mk) - 1;
    unsigned aS = __shfl(above, src, 64);
    unsigned c0 = __shfl(c.x, src, 64), c1 = __shfl(c.y, src, 64);
    unsigned c2 = __shfl(c.z, src, 64), c3 = __shfl(c.w, src, 64);
    unsigned a3 = aS, a2 = a3 + c3, a1 = a2 + c2, a0 = a1 + c1;
    unsigned b, a;
    if      (a3 < rr_in && rr_in <= a3 + c3) { b = 3u; a = a3; }
    else if (a2 < rr_in && rr_in <= a2 + c2) { b = 2u; a = a2; }
    else if (a1 < rr_in && rr_in <= a1 + c1) { b = 1u; a = a1; }
    else                                     { b = 0u; a = a0; }
    sub = ((unsigned)src << 2) | b;
    rr  = rr_in - a;
}

// duplicate-aware rank resolve among finalists (wave-level, redundant per wave)
__device__ __forceinline__ unsigned resolve_fin(const unsigned* fin, unsigned K,
                                                unsigned rr, int lane) {
    unsigned myk = fin[lane < (int)K ? lane : 0];
    unsigned gt = 0, eq = 0;
    for (unsigned i = 0; i < K; ++i) {
        unsigned v = fin[i];                 // LDS broadcast
        gt += (v > myk) ? 1u : 0u;
        eq += (v == myk) ? 1u : 0u;
    }
    bool hit = (lane < (int)K) && (gt < rr) && (rr <= gt + eq);
    unsigned long long mk = __ballot(hit);
    if (mk == 0ull) return fin[0];           // cap-overflow fallback
    int src = __ffsll(mk) - 1;
    return __shfl(myk, src, 64);
}

// windowed suffix scan over a 1024-bin hist: resolves both target bins (wave-level)
__device__ __forceinline__ void window_scan(const unsigned* hist, int lane, unsigned topbin,
                                            unsigned rankHi, unsigned rankLo,
                                            unsigned& bin0, unsigned& rr0,
                                            unsigned& bin1, unsigned& rr1) {
    bin0 = 0; rr0 = rankHi;
    bin1 = 0; rr1 = rankLo;
    int wstart = (int)topbin;
    bool f0 = false, f1 = false;
    unsigned base = 0u;
    while (!(f0 && f1)) {
        int b = wstart - lane;
        unsigned c = (b >= 0) ? hist[b] : 0u;
        unsigned incl, tot; wscan(c, lane, incl, tot);
        unsigned above = base + incl - c;
        unsigned cum   = base + incl;
        if (!f0) {
            bool hit = (above < rr0) && (rr0 <= cum);
            unsigned long long mk = __ballot(hit);
            if (mk) { int s = __ffsll(mk) - 1; bin0 = (unsigned)(wstart - s);
                      rr0 -= __shfl(above, s, 64); f0 = true; }
        }
        if (!f1) {
            bool hit = (above < rr1) && (rr1 <= cum);
            unsigned long long mk = __ballot(hit);
            if (mk) { int s = __ffsll(mk) - 1; bin1 = (unsigned)(wstart - s);
                      rr1 -= __shfl(above, s, 64); f1 = true; }
        }
        base += tot;
        wstart -= 64;
    }
}

// ------------- kernel 3: TWO ROWS PER BLOCK; barriers amortized, chains interleaved -------------
__global__ __launch_bounds__(NT)
void k_select_apply(const float4* __restrict__ x4, const float4* __restrict__ factor4,
                    const float4* __restrict__ invf4, const float4* __restrict__ mean4,
                    float4* __restrict__ out4, int rankHi, int rankLo, int B) {
    __shared__ __align__(16) unsigned hist[2][NBINS];   // 8 KB
    __shared__ __align__(16) unsigned h8[2][2][256];    // 4 KB  [row][target]
    __shared__ unsigned fin[2][2][CAPF];                // 512 B
    __shared__ unsigned fcnt[2][2];
    __shared__ unsigned smax[2][4];

    const int t    = threadIdx.x;
    const int wid  = t >> 6;
    const int lane = t & 63;
    const int row0 = blockIdx.x * 2;
    const int row1v = (row0 + 1 < B) ? row0 + 1 : row0;   // degenerate-safe
    const size_t rb[2] = { (size_t)row0 * FEAT4, (size_t)row1v * FEAT4 };

    // ---- zero ----
    *reinterpret_cast<uint4*>(&hist[0][4 * t]) = make_uint4(0u,0u,0u,0u);
    *reinterpret_cast<uint4*>(&hist[1][4 * t]) = make_uint4(0u,0u,0u,0u);
    h8[0][0][t] = 0u; h8[0][1][t] = 0u; h8[1][0][t] = 0u; h8[1][1][t] = 0u;
    if (t < 4) fcnt[t >> 1][t & 1] = 0u;
    __syncthreads();                                   // B1

    // ---- phase A (both rows): keygen + 10-bit histogram + wave max ----
    unsigned kk[2][16];
    #pragma unroll
    for (int r = 0; r < 2; ++r) {
        unsigned wm = 0u;
        #pragma unroll
        for (int jj = 0; jj < 4; ++jj) {
            int v = t + NT * jj;
            float4 X  = x4[rb[r] + v];
            float4 Fa = factor4[v];
            unsigned k0 = fkey(X.x * Fa.x), k1 = fkey(X.y * Fa.y);
            unsigned k2 = fkey(X.z * Fa.z), k3 = fkey(X.w * Fa.w);
            kk[r][4*jj+0] = k0; kk[r][4*jj+1] = k1;
            kk[r][4*jj+2] = k2; kk[r][4*jj+3] = k3;
            wm = max(max(max(wm, k0), max(k1, k2)), k3);
            atomicAdd(&hist[r][k0 >> 22], 1u);
            atomicAdd(&hist[r][k1 >> 22], 1u);
            atomicAdd(&hist[r][k2 >> 22], 1u);
            atomicAdd(&hist[r][k3 >> 22], 1u);
        }
        #pragma unroll
        for (int off = 32; off > 0; off >>= 1)
            wm = max(wm, (unsigned)__shfl_xor(wm, off, 64));
        if (lane == 0) smax[r][wid] = wm;
    }
    __syncthreads();                                   // B2

    // ---- phase B (both rows, redundant per wave): windowed suffix scans ----
    unsigned bin0[2], rr0[2], bin1[2], rr1[2];
    #pragma unroll
    for (int r = 0; r < 2; ++r) {
        unsigned bm = max(max(smax[r][0], smax[r][1]), max(smax[r][2], smax[r][3]));
        window_scan(&hist[r][0], lane, bm >> 22, (unsigned)rankHi, (unsigned)rankLo,
                    bin0[r], rr0[r], bin1[r], rr1[r]);
    }

    // ---- phase C (both rows): 8-bit sub-histograms ----
    #pragma unroll
    for (int r = 0; r < 2; ++r) {
        #pragma unroll
        for (int j = 0; j < 16; ++j) {
            unsigned k = kk[r][j];
            unsigned d = k >> 22;
            if (d == bin1[r]) atomicAdd(&h8[r][1][(k >> 14) & 255u], 1u);
            if (d == bin0[r]) atomicAdd(&h8[r][0][(k >> 14) & 255u], 1u);
        }
    }
    __syncthreads();                                   // B3

    // ---- phase D (both rows × both targets, redundant per wave) ----
    unsigned sub0[2], rrf0[2], sub1[2], rrf1[2];
    #pragma unroll
    for (int r = 0; r < 2; ++r) {
        select256(&h8[r][0][0], lane, rr0[r], sub0[r], rrf0[r]);
        select256(&h8[r][1][0], lane, rr1[r], sub1[r], rrf1[r]);
    }

    // ---- phase E (both rows): finalist gather from register keys ----
    #pragma unroll
    for (int r = 0; r < 2; ++r) {
        unsigned pre0 = (bin0[r] << 8) | sub0[r];
        unsigned pre1 = (bin1[r] << 8) | sub1[r];
        #pragma unroll
        for (int j = 0; j < 16; ++j) {
            unsigned k = kk[r][j];
            unsigned p = k >> 14;
            if (p == pre1) { unsigned f = atomicAdd(&fcnt[r][1], 1u); if (f < CAPF) fin[r][1][f] = k; }
            if (p == pre0) { unsigned f = atomicAdd(&fcnt[r][0], 1u); if (f < CAPF) fin[r][0][f] = k; }
        }
    }
    __syncthreads();                                   // B4

    // ---- phase F + G per row ----
    #pragma unroll
    for (int r = 0; r < 2; ++r) {
        unsigned K0 = fcnt[r][0]; if (K0 > CAPF) K0 = CAPF;
        unsigned K1 = fcnt[r][1]; if (K1 > CAPF) K1 = CAPF;
        const unsigned keyHi = resolve_fin(&fin[r][0][0], K0, rrf0[r], lane);
        const unsigned keyLo = resolve_fin(&fin[r][1][0], K1, rrf1[r], lane);
        if (r == 1 && row0 + 1 >= B) break;
        #pragma unroll
        for (int jj = 0; jj < 4; ++jj) {
            int v = t + NT * jj;
            float4 Fi = invf4[v];
            float4 M  = mean4[v];
            unsigned k0 = kk[r][4*jj+0], k1 = kk[r][4*jj+1];
            unsigned k2 = kk[r][4*jj+2], k3 = kk[r][4*jj+3];
            float xp0 = fkey_inv(k0), xp1 = fkey_inv(k1);
            float xp2 = fkey_inv(k2), xp3 = fkey_inv(k3);
            vfloat4 o;
            o.x = (k0 <= keyHi) ? ((k0 >= keyLo) ? __builtin_fmaf(xp0, Fi.x, -M.x) : -M.x) : 0.0f;
            o.y = (k1 <= keyHi) ? ((k1 >= keyLo) ? __builtin_fmaf(xp1, Fi.y, -M.y) : -M.y) : 0.0f;
            o.z = (k2 <= keyHi) ? ((k2 >= keyLo) ? __builtin_fmaf(xp2, Fi.z, -M.z) : -M.z) : 0.0f;
            o.w = (k3 <= keyHi) ? ((k3 >= keyLo) ? __builtin_fmaf(xp3, Fi.w, -M.w) : -M.w) : 0.0f;
            __builtin_nontemporal_store(o, reinterpret_cast<vfloat4*>(&out4[rb[r] + v]));
        }
    }
}

extern "C" void kernel_launch(void* const* d_in, const int* in_sizes, int n_in,
                              void* d_out, int out_size, void* d_ws, size_t ws_size,
                              hipStream_t stream) {
    const float* x  = (const float*)d_in[0];
    const float* aa = (const float*)d_in[1];
    float* out = (float*)d_out;

    const int F   = in_sizes[1];          // 4096
    const int B   = in_sizes[0] / F;      // 8192
    const int F4v = F / 4;
    const int rankLo = (int)((double)F * 0.05) + TOP_IG;   // 211
    const int rankHi = TOP_IG;                              // 7

    int nChunks = 256;
    while (nChunks > 1 &&
           ((size_t)nChunks + 3) * (size_t)F * sizeof(float) > ws_size)
        nChunks >>= 1;
    if (nChunks > B) nChunks = B;

    float* part   = (float*)d_ws;
    float* mean   = part + (size_t)nChunks * F;
    float* factor = mean + F;
    float* invf   = factor + F;
    int rpc = (B + nChunks - 1) / nChunks;

    dim3 g1((F4v + NT1 - 1) / NT1, nChunks);
    k_colsum_partial<<<g1, NT1, 0, stream>>>((const float4*)x, (float4*)part, B, F4v, rpc);

    k_finalize_stats<<<dim3((F4v + 15) / 16), NT, 0, stream>>>(
        (const float4*)part, (const float4*)aa, (float4*)mean, (float4*)factor,
        (float4*)invf, B, F4v, nChunks);

    k_select_apply<<<dim3((B + 1) / 2), NT, 0, stream>>>(
        (const float4*)x, (const float4*)factor, (const float4*)invf, (const float4*)mean,
        (float4*)out, rankHi, rankLo, B);
}

// Round 16
// 81.520 us; speedup vs baseline: 1.2182x; 1.2182x over previous
//
#include <hip/hip_runtime.h>
#include <cstdint>
#include <cmath>

#define DENSITY   0.05f
#define TOP_IG    7
#define NT        256
#define NT1       64
#define FEAT      4096
#define FEAT4     1024
#define NBINS     1024     // 10-bit pass-1 digit: key>>22 (sign+exp+1 mantissa bit)
#define CAPF      32       // finalist cap (typ 1-3)

typedef float vfloat4 __attribute__((ext_vector_type(4)));

// monotonic float -> uint order key (ascending float == ascending key)
__device__ __forceinline__ unsigned fkey(float f) {
    unsigned u = __float_as_uint(f);
    return (u & 0x80000000u) ? ~u : (u | 0x80000000u);
}
__device__ __forceinline__ float fkey_inv(unsigned k) {
    unsigned u = (k & 0x80000000u) ? (k & 0x7fffffffu) : ~k;
    return __uint_as_float(u);
}

// ---------------- kernel 1: chunked column partial sums (R12, frozen) ----------------
__global__ __launch_bounds__(NT1)
void k_colsum_partial(const float4* __restrict__ x4, float4* __restrict__ part4,
                      int B, int F4v, int rowsPerChunk) {
    int cg = blockIdx.x * NT1 + threadIdx.x;
    if (cg >= F4v) return;
    int r0 = blockIdx.y * rowsPerChunk;
    int r1 = r0 + rowsPerChunk; if (r1 > B) r1 = B;
    float4 s0 = make_float4(0.f,0.f,0.f,0.f), s1 = s0, s2 = s0, s3 = s0;
    int r = r0;
    for (; r + 4 <= r1; r += 4) {
        float4 a = x4[(size_t)(r+0) * F4v + cg];
        float4 b = x4[(size_t)(r+1) * F4v + cg];
        float4 c = x4[(size_t)(r+2) * F4v + cg];
        float4 d = x4[(size_t)(r+3) * F4v + cg];
        s0.x += a.x; s0.y += a.y; s0.z += a.z; s0.w += a.w;
        s1.x += b.x; s1.y += b.y; s1.z += b.z; s1.w += b.w;
        s2.x += c.x; s2.y += c.y; s2.z += c.z; s2.w += c.w;
        s3.x += d.x; s3.y += d.y; s3.z += d.z; s3.w += d.w;
    }
    for (; r < r1; ++r) {
        float4 a = x4[(size_t)r * F4v + cg];
        s0.x += a.x; s0.y += a.y; s0.z += a.z; s0.w += a.w;
    }
    float4 s = make_float4(s0.x+s1.x+s2.x+s3.x, s0.y+s1.y+s2.y+s3.y,
                           s0.z+s1.z+s2.z+s3.z, s0.w+s1.w+s2.w+s3.w);
    part4[(size_t)blockIdx.y * F4v + cg] = s;
}

// ------- kernel 2: reduce partials -> mean; factor + invFactor (R12, frozen) -------
__global__ __launch_bounds__(NT)
void k_finalize_stats(const float4* __restrict__ part4, const float4* __restrict__ aa4,
                      float4* __restrict__ mean4, float4* __restrict__ factor4,
                      float4* __restrict__ invf4, int B, int F4v, int nChunks) {
    __shared__ float4 red[16][17];
    const int c  = threadIdx.x >> 4;
    const int s  = threadIdx.x & 15;
    const int cg = blockIdx.x * 16 + c;
    float4 acc = make_float4(0.f, 0.f, 0.f, 0.f);
    if (cg < F4v) {
        for (int ch = s; ch < nChunks; ch += 16) {
            float4 v = part4[(size_t)ch * F4v + cg];
            acc.x += v.x; acc.y += v.y; acc.z += v.z; acc.w += v.w;
        }
    }
    red[c][s] = acc;
    __syncthreads();
    if (s == 0 && cg < F4v) {
        float4 t = red[c][0];
        #pragma unroll
        for (int i = 1; i < 16; ++i) {
            float4 v = red[c][i];
            t.x += v.x; t.y += v.y; t.z += v.z; t.w += v.w;
        }
        float invB = 1.0f / (float)B;
        mean4[cg] = make_float4(t.x * invB, t.y * invB, t.z * invB, t.w * invB);
        float4 a = aa4[cg];
        float fx = (float)exp((double)(DENSITY - a.x));
        float fy = (float)exp((double)(DENSITY - a.y));
        float fz = (float)exp((double)(DENSITY - a.z));
        float fw = (float)exp((double)(DENSITY - a.w));
        factor4[cg] = make_float4(fx, fy, fz, fw);
        invf4[cg]   = make_float4(1.0f / fx, 1.0f / fy, 1.0f / fz, 1.0f / fw);
    }
}

// wave inclusive scan + total of per-lane value
__device__ __forceinline__ void wscan(unsigned T, int lane, unsigned& incl, unsigned& tot) {
    unsigned P = T;
    #pragma unroll
    for (int off = 1; off < 64; off <<= 1) {
        unsigned n = __shfl_up(P, off, 64);
        if (lane >= off) P += n;
    }
    incl = P;
    tot = __shfl(P, 63, 64);
}

// find rank rr_in in a 256-bin histogram (lane owns 4 bins via uint4) — wave-level
__device__ __forceinline__ void select256(const unsigned* h, int lane,
                                          unsigned rr_in, unsigned& sub, unsigned& rr) {
    uint4 c = *reinterpret_cast<const uint4*>(&h[lane << 2]);
    unsigned T = c.x + c.y + c.z + c.w;
    unsigned incl, tot; wscan(T, lane, incl, tot);
    unsigned above = tot - incl;
    bool hit = (above < rr_in) && (rr_in <= above + T);
    unsigned long long mk = __ballot(hit);
    int src = __ffsll(mk) - 1;
    unsigned aS = __shfl(above, src, 64);
    unsigned c0 = __shfl(c.x, src, 64), c1 = __shfl(c.y, src, 64);
    unsigned c2 = __shfl(c.z, src, 64), c3 = __shfl(c.w, src, 64);
    unsigned a3 = aS, a2 = a3 + c3, a1 = a2 + c2, a0 = a1 + c1;
    unsigned b, a;
    if      (a3 < rr_in && rr_in <= a3 + c3) { b = 3u; a = a3; }
    else if (a2 < rr_in && rr_in <= a2 + c2) { b = 2u; a = a2; }
    else if (a1 < rr_in && rr_in <= a1 + c1) { b = 1u; a = a1; }
    else                                     { b = 0u; a = a0; }
    sub = ((unsigned)src << 2) | b;
    rr  = rr_in - a;
}

// duplicate-aware rank resolve among finalists (wave-level, redundant per wave)
__device__ __forceinline__ unsigned resolve_fin(const unsigned* fin, unsigned K,
                                                unsigned rr, int lane) {
    unsigned myk = fin[lane < (int)K ? lane : 0];
    unsigned gt = 0, eq = 0;
    for (unsigned i = 0; i < K; ++i) {
        unsigned v = fin[i];                 // LDS broadcast
        gt += (v > myk) ? 1u : 0u;
        eq += (v == myk) ? 1u : 0u;
    }
    bool hit = (lane < (int)K) && (gt < rr) && (rr <= gt + eq);
    unsigned long long mk = __ballot(hit);
    if (mk == 0ull) return fin[0];           // cap-overflow fallback
    int src = __ffsll(mk) - 1;
    return __shfl(myk, src, 64);
}

// ------------- kernel 3: block-per-row dual select; G reconstructs x from keys (R12, frozen) -------------
__global__ __launch_bounds__(NT)
void k_select_apply(const float4* __restrict__ x4, const float4* __restrict__ factor4,
                    const float4* __restrict__ invf4, const float4* __restrict__ mean4,
                    float4* __restrict__ out4, int rankHi, int rankLo) {
    __shared__ __align__(16) unsigned hist[NBINS];   // 4 KB
    __shared__ __align__(16) unsigned h8[2][256];    // 2 KB
    __shared__ unsigned fin[2][CAPF];                // 256 B
    __shared__ unsigned fcnt[2];
    __shared__ unsigned smax[4];

    const int t    = threadIdx.x;
    const int wid  = t >> 6;
    const int lane = t & 63;
    const size_t rowBase = (size_t)blockIdx.x * FEAT4;

    // ---- zero ----
    *reinterpret_cast<uint4*>(&hist[4 * t]) = make_uint4(0u,0u,0u,0u);
    h8[0][t] = 0u; h8[1][t] = 0u;
    if (t < 2) fcnt[t] = 0u;
    __syncthreads();                                   // B1

    // ---- phase A: keygen (keys stay in VGPRs) + 10-bit histogram + wave max ----
    unsigned kk[16];
    unsigned wm = 0u;
    #pragma unroll
    for (int jj = 0; jj < 4; ++jj) {
        int v = t + NT * jj;
        float4 X  = x4[rowBase + v];
        float4 Fa = factor4[v];
        unsigned k0 = fkey(X.x * Fa.x), k1 = fkey(X.y * Fa.y);
        unsigned k2 = fkey(X.z * Fa.z), k3 = fkey(X.w * Fa.w);
        kk[4*jj+0] = k0; kk[4*jj+1] = k1; kk[4*jj+2] = k2; kk[4*jj+3] = k3;
        wm = max(max(max(wm, k0), max(k1, k2)), k3);
        atomicAdd(&hist[k0 >> 22], 1u);
        atomicAdd(&hist[k1 >> 22], 1u);
        atomicAdd(&hist[k2 >> 22], 1u);
        atomicAdd(&hist[k3 >> 22], 1u);
    }
    #pragma unroll
    for (int off = 32; off > 0; off >>= 1)
        wm = max(wm, (unsigned)__shfl_xor(wm, off, 64));
    if (lane == 0) smax[wid] = wm;
    __syncthreads();                                   // B2

    // ---- phase B: windowed suffix scan from the top bin (redundant per wave) ----
    unsigned bin0 = 0, rr0 = (unsigned)rankHi;         // rank 7 (top_ig)
    unsigned bin1 = 0, rr1 = (unsigned)rankLo;         // rank 211 (kth)
    {
        unsigned bm = max(max(smax[0], smax[1]), max(smax[2], smax[3]));
        int wstart = (int)(bm >> 22);
        bool f0 = false, f1 = false;
        unsigned base = 0u;
        while (!(f0 && f1)) {
            int b = wstart - lane;
            unsigned c = (b >= 0) ? hist[b] : 0u;
            unsigned incl, tot; wscan(c, lane, incl, tot);
            unsigned above = base + incl - c;
            unsigned cum   = base + incl;
            if (!f0) {
                bool hit = (above < rr0) && (rr0 <= cum);
                unsigned long long mk = __ballot(hit);
                if (mk) { int s = __ffsll(mk) - 1; bin0 = (unsigned)(wstart - s);
                          rr0 -= __shfl(above, s, 64); f0 = true; }
            }
            if (!f1) {
                bool hit = (above < rr1) && (rr1 <= cum);
                unsigned long long mk = __ballot(hit);
                if (mk) { int s = __ffsll(mk) - 1; bin1 = (unsigned)(wstart - s);
                          rr1 -= __shfl(above, s, 64); f1 = true; }
            }
            base += tot;
            wstart -= 64;
        }
    }

    // ---- phase C: 8-bit sub-histograms for both target bins ----
    #pragma unroll
    for (int j = 0; j < 16; ++j) {
        unsigned k = kk[j];
        unsigned d = k >> 22;
        if (d == bin1) atomicAdd(&h8[1][(k >> 14) & 255u], 1u);
        if (d == bin0) atomicAdd(&h8[0][(k >> 14) & 255u], 1u);
    }
    __syncthreads();                                   // B3

    // ---- phase D: sub-digit select, both targets, redundant per wave ----
    unsigned sub0, rrf0; select256(&h8[0][0], lane, rr0, sub0, rrf0);
    unsigned sub1, rrf1; select256(&h8[1][0], lane, rr1, sub1, rrf1);

    // ---- phase E: finalist gather by re-scanning register keys (18-bit prefix) ----
    {
        unsigned pre0 = (bin0 << 8) | sub0;
        unsigned pre1 = (bin1 << 8) | sub1;
        #pragma unroll
        for (int j = 0; j < 16; ++j) {
            unsigned k = kk[j];
            unsigned p = k >> 14;
            if (p == pre1) { unsigned f = atomicAdd(&fcnt[1], 1u); if (f < CAPF) fin[1][f] = k; }
            if (p == pre0) { unsigned f = atomicAdd(&fcnt[0], 1u); if (f < CAPF) fin[0][f] = k; }
        }
    }
    __syncthreads();                                   // B4

    // ---- phase F: exact rank among finalists, redundant per wave ----
    unsigned K0 = fcnt[0]; if (K0 > CAPF) K0 = CAPF;
    unsigned K1 = fcnt[1]; if (K1 > CAPF) K1 = CAPF;
    const unsigned keyHi = resolve_fin(&fin[0][0], K0, rrf0, lane);
    const unsigned keyLo = resolve_fin(&fin[1][0], K1, rrf1, lane);

    // ---- phase G: reconstruct x from keys (NO x re-read), apply masks, nt-store ----
    #pragma unroll
    for (int jj = 0; jj < 4; ++jj) {
        int v = t + NT * jj;
        float4 Fi = invf4[v];
        float4 M  = mean4[v];
        unsigned k0 = kk[4*jj+0], k1 = kk[4*jj+1], k2 = kk[4*jj+2], k3 = kk[4*jj+3];
        float xp0 = fkey_inv(k0), xp1 = fkey_inv(k1);
        float xp2 = fkey_inv(k2), xp3 = fkey_inv(k3);
        vfloat4 o;
        o.x = (k0 <= keyHi) ? ((k0 >= keyLo) ? __builtin_fmaf(xp0, Fi.x, -M.x) : -M.x) : 0.0f;
        o.y = (k1 <= keyHi) ? ((k1 >= keyLo) ? __builtin_fmaf(xp1, Fi.y, -M.y) : -M.y) : 0.0f;
        o.z = (k2 <= keyHi) ? ((k2 >= keyLo) ? __builtin_fmaf(xp2, Fi.z, -M.z) : -M.z) : 0.0f;
        o.w = (k3 <= keyHi) ? ((k3 >= keyLo) ? __builtin_fmaf(xp3, Fi.w, -M.w) : -M.w) : 0.0f;
        __builtin_nontemporal_store(o, reinterpret_cast<vfloat4*>(&out4[rowBase + v]));
    }
}

extern "C" void kernel_launch(void* const* d_in, const int* in_sizes, int n_in,
                              void* d_out, int out_size, void* d_ws, size_t ws_size,
                              hipStream_t stream) {
    const float* x  = (const float*)d_in[0];
    const float* aa = (const float*)d_in[1];
    float* out = (float*)d_out;

    const int F   = in_sizes[1];          // 4096
    const int B   = in_sizes[0] / F;      // 8192
    const int F4v = F / 4;
    const int rankLo = (int)((double)F * 0.05) + TOP_IG;   // 211
    const int rankHi = TOP_IG;                              // 7

    int nChunks = 256;
    while (nChunks > 1 &&
           ((size_t)nChunks + 3) * (size_t)F * sizeof(float) > ws_size)
        nChunks >>= 1;
    if (nChunks > B) nChunks = B;

    float* part   = (float*)d_ws;
    float* mean   = part + (size_t)nChunks * F;
    float* factor = mean + F;
    float* invf   = factor + F;
    int rpc = (B + nChunks - 1) / nChunks;

    dim3 g1((F4v + NT1 - 1) / NT1, nChunks);
    k_colsum_partial<<<g1, NT1, 0, stream>>>((const float4*)x, (float4*)part, B, F4v, rpc);

    k_finalize_stats<<<dim3((F4v + 15) / 16), NT, 0, stream>>>(
        (const float4*)part, (const float4*)aa, (float4*)mean, (float4*)factor,
        (float4*)invf, B, F4v, nChunks);

    k_select_apply<<<dim3(B), NT, 0, stream>>>(
        (const float4*)x, (const float4*)factor, (const float4*)invf, (const float4*)mean,
        (float4*)out, rankHi, rankLo);
}